// Round 5
// baseline (6451.807 us; speedup 1.0000x reference)
//
#include <hip/hip_runtime.h>
#include <hip/hip_cooperative_groups.h>

namespace cg = cooperative_groups;

#define NB    4
#define H     512
#define W     512
#define ITERS 30
#define TOLF  1e-05f
#define TOTAL (NB*H*W*3)     // 3,145,728
#define BLK   256
#define NBLKS 1024           // 4 images x 16x16 tiles of 32x32
#define LRS   36             // lat row stride
#define LPS   (36*36)
#define RRS   34
#define RPS   (34*34)

__device__ __forceinline__ int refl(int v, int n) {
    if (v < 0)  return -v;
    if (v >= n) return 2 * n - 2 - v;
    return v;
}

// 3x3 conv from LDS around center pointer s (row stride rs), weights w
// laid out [(dy*3+dx)*3 + c], channel c.
__device__ __forceinline__ float conv3x3(const float* s, int rs,
                                         const float* __restrict__ w, int c) {
    float a = 0.f;
    a = fmaf(s[-rs - 1], w[0  + c], a);
    a = fmaf(s[-rs    ], w[3  + c], a);
    a = fmaf(s[-rs + 1], w[6  + c], a);
    a = fmaf(s[-1     ], w[9  + c], a);
    a = fmaf(s[0      ], w[12 + c], a);
    a = fmaf(s[1      ], w[15 + c], a);
    a = fmaf(s[rs - 1 ], w[18 + c], a);
    a = fmaf(s[rs     ], w[21 + c], a);
    a = fmaf(s[rs + 1 ], w[24 + c], a);
    return a;
}

// frame pixels (outer 2-wide ring of the 32x32 interior), t in [0,240)
__device__ __forceinline__ void frame_px(int t, int& i, int& j) {
    if (t < 128) {                       // rows 0,1,30,31 x full width
        const int s = t >> 5;
        i = (s & 1) + (s >> 1) * 30;
        j = t & 31;
    } else {                             // cols 0,1,30,31 x rows 2..29
        const int u = t - 128;
        const int s = u / 28;
        j = (s & 1) + (s >> 1) * 30;
        i = 2 + (u - s * 28);
    }
}

// halo pixels (ring of the 36x36 tile outside the 32x32 interior), t in [0,272)
__device__ __forceinline__ void halo_px(int t, int& i, int& j) {
    if (t < 144) {                       // rows 0,1,34,35 x full 36
        const int s = t / 36;
        i = (s & 1) + (s >> 1) * 34;
        j = t - s * 36;
    } else {                             // cols 0,1,34,35 x rows 2..33
        const int u = t - 144;
        const int s = u >> 5;
        j = (s & 1) + (s >> 1) * 34;
        i = 2 + (u & 31);
    }
}

// Persistent cooperative kernel: all 30 RL iterations in one dispatch.
// Latent tile lives in LDS; per-iteration cross-tile halo exchange via
// double-buffered global frame buffers + grid.sync().
__global__ __launch_bounds__(BLK, 4) void rl_persist(
    const float* __restrict__ inputs,
    const float* __restrict__ gk,
    const float* __restrict__ gkf,
    float* __restrict__ out,
    float* __restrict__ fb0, float* __restrict__ fb1,
    float* __restrict__ pa0, float* __restrict__ pa1)
{
    cg::grid_group grid = cg::this_grid();

    __shared__ float  lat[3 * LPS];      // 15552 B
    __shared__ float  rbt[3 * RPS];      // 13872 B
    __shared__ double red[4];
    __shared__ float  wred[4];
    __shared__ int    s_done;

    const int tid  = threadIdx.x;
    const int lane = tid & 63;
    const int wid  = tid >> 6;
    const int b    = blockIdx.x;
    const int n    = b >> 8;
    const int r    = b & 255;
    const int ty0  = (r >> 4) << 5;
    const int tx0  = (r & 15) << 5;
    const bool ye0 = (ty0 == 0), ye1 = (ty0 + 32 == H);
    const bool xe0 = (tx0 == 0), xe1 = (tx0 + 32 == W);
    const bool edge = ye0 | ye1 | xe0 | xe1;

    const size_t nbase = (size_t)n * (H * W * 3);
    const float* inp_n = inputs + nbase;

    if (tid == 0) s_done = 0;

    // ---- init: latent interior = inputs ----
    for (int p = tid; p < 1024; p += BLK) {
        const int i = p >> 5, j = p & 31;
        const float* ip = inp_n + ((size_t)(ty0 + i) * W + (tx0 + j)) * 3;
        const int l = (i + 2) * LRS + (j + 2);
        lat[0 * LPS + l] = ip[0];
        lat[1 * LPS + l] = ip[1];
        lat[2 * LPS + l] = ip[2];
    }
    __syncthreads();
    // initial frames -> fb0
    for (int t = tid; t < 240; t += BLK) {
        int i, j; frame_px(t, i, j);
        float* fp = fb0 + nbase + ((size_t)(ty0 + i) * W + (tx0 + j)) * 3;
        const int l = (i + 2) * LRS + (j + 2);
        fp[0] = lat[0 * LPS + l];
        fp[1] = lat[1 * LPS + l];
        fp[2] = lat[2 * LPS + l];
    }
    __threadfence();
    grid.sync();

    for (int it = 0; it < ITERS; ++it) {
        const float* fbr = (it & 1) ? fb1 : fb0;
        float*       fbw = (it & 1) ? fb0 : fb1;
        const float* prd = (it & 1) ? pa0 : pa1;   // written at it-1
        float*       pwr = (it & 1) ? pa1 : pa0;

        // ---- done check from previous iteration's partials ----
        if (it > 0) {
            double a = 0.0;
            #pragma unroll
            for (int k2 = 0; k2 < NBLKS / BLK; ++k2)
                a += (double)prd[tid + k2 * BLK];
            #pragma unroll
            for (int off = 32; off; off >>= 1) a += __shfl_down(a, off, 64);
            if (lane == 0) red[wid] = a;
            __syncthreads();
            if (tid == 0) {
                const double s = red[0] + red[1] + red[2] + red[3];
                const float mean = (float)(s / (double)TOTAL);
                if (fabsf(1.0f - mean) < TOLF) s_done = 1;
            }
        }

        // ---- fill halo (in-image part) from frame buffer ----
        for (int t = tid; t < 272; t += BLK) {
            int i, j; halo_px(t, i, j);
            const int gy = ty0 - 2 + i, gx = tx0 - 2 + j;
            if (gy >= 0 && gy < H && gx >= 0 && gx < W) {
                const float* fp = fbr + nbase + ((size_t)gy * W + gx) * 3;
                const int l = i * LRS + j;
                lat[0 * LPS + l] = fp[0];
                lat[1 * LPS + l] = fp[1];
                lat[2 * LPS + l] = fp[2];
            }
        }
        __syncthreads();

        // ---- reflect fixups (edge tiles): columns, then rows ----
        if (xe0) {
            for (int t = tid; t < 216; t += BLK) {
                const int i = t / 6, rr = t - i * 6, c = rr >> 1, col = rr & 1;
                lat[c * LPS + i * LRS + col] = lat[c * LPS + i * LRS + (4 - col)];
            }
        } else if (xe1) {
            for (int t = tid; t < 216; t += BLK) {
                const int i = t / 6, rr = t - i * 6, c = rr >> 1, col = rr & 1;
                lat[c * LPS + i * LRS + 34 + col] = lat[c * LPS + i * LRS + (32 - col)];
            }
        }
        __syncthreads();
        if (ye0) {
            for (int t = tid; t < 216; t += BLK) {
                const int c = t / 72, rr = t - c * 72, row = rr / 36, j = rr - row * 36;
                lat[c * LPS + row * LRS + j] = lat[c * LPS + (4 - row) * LRS + j];
            }
        } else if (ye1) {
            for (int t = tid; t < 216; t += BLK) {
                const int c = t / 72, rr = t - c * 72, row = rr / 36, j = rr - row * 36;
                lat[c * LPS + (34 + row) * LRS + j] = lat[c * LPS + (32 - row) * LRS + j];
            }
        }
        __syncthreads();

        // ---- rb = inputs / conv(lat, k), 34x34 into LDS ----
        if (!edge) {
            for (int p = tid; p < RPS; p += BLK) {
                const int i = p / 34, j = p - i * 34;
                const float* ip = inp_n + ((size_t)(ty0 - 1 + i) * W + (tx0 - 1 + j)) * 3;
                const int l = (i + 1) * LRS + (j + 1);
                #pragma unroll
                for (int c = 0; c < 3; ++c) {
                    const float acc = conv3x3(lat + c * LPS + l, LRS, gk, c);
                    rbt[c * RPS + p] = ip[c] * __builtin_amdgcn_rcpf(acc);
                }
            }
        } else {
            for (int p = tid; p < RPS; p += BLK) {
                const int i = p / 34, j = p - i * 34;
                const int ry = refl(ty0 - 1 + i, H);
                const int rx = refl(tx0 - 1 + j, W);
                const int ti = ry - (ty0 - 2), tj = rx - (tx0 - 2);
                const float* ip = inp_n + ((size_t)ry * W + rx) * 3;
                const int l = ti * LRS + tj;
                #pragma unroll
                for (int c = 0; c < 3; ++c) {
                    const float acc = conv3x3(lat + c * LPS + l, LRS, gk, c);
                    rbt[c * RPS + p] = ip[c] * __builtin_amdgcn_rcpf(acc);
                }
            }
        }
        __syncthreads();

        // ---- e = conv(rb, kf); latent *= e (gated); block esum ----
        const int sd = s_done;
        float esum = 0.0f;
        for (int p = tid; p < 1024; p += BLK) {
            const int i = p >> 5, j = p & 31;
            const int lr = (i + 1) * RRS + (j + 1);
            const int ll = (i + 2) * LRS + (j + 2);
            #pragma unroll
            for (int c = 0; c < 3; ++c) {
                const float e = conv3x3(rbt + c * RPS + lr, RRS, gkf, c);
                esum += e;
                if (!sd) lat[c * LPS + ll] *= e;
            }
        }
        #pragma unroll
        for (int off = 32; off; off >>= 1) esum += __shfl_down(esum, off, 64);
        if (lane == 0) wred[wid] = esum;
        __syncthreads();                    // wred ready AND lat updates done

        if (it < ITERS - 1) {
            if (tid == 0) pwr[b] = wred[0] + wred[1] + wred[2] + wred[3];
            // write updated frames for neighbors
            for (int t = tid; t < 240; t += BLK) {
                int i, j; frame_px(t, i, j);
                float* fp = fbw + nbase + ((size_t)(ty0 + i) * W + (tx0 + j)) * 3;
                const int l = (i + 2) * LRS + (j + 2);
                fp[0] = lat[0 * LPS + l];
                fp[1] = lat[1 * LPS + l];
                fp[2] = lat[2 * LPS + l];
            }
            __threadfence();
            grid.sync();
        }
    }

    // ---- write final latent to output ----
    for (int p = tid; p < 1024; p += BLK) {
        const int i = p >> 5, j = p & 31;
        float* op = out + nbase + ((size_t)(ty0 + i) * W + (tx0 + j)) * 3;
        const int l = (i + 2) * LRS + (j + 2);
        op[0] = lat[0 * LPS + l];
        op[1] = lat[1 * LPS + l];
        op[2] = lat[2 * LPS + l];
    }
}

extern "C" void kernel_launch(void* const* d_in, const int* in_sizes, int n_in,
                              void* d_out, int out_size, void* d_ws, size_t ws_size,
                              hipStream_t stream) {
    const float* inputs = (const float*)d_in[0];
    const float* kern   = (const float*)d_in[1];
    const float* kernf  = (const float*)d_in[2];
    float* latent = (float*)d_out;

    // ws: partials A | partials B | frame buf 0 | frame buf 1
    char* ws = (char*)d_ws;
    float* pa0 = (float*)(ws);
    float* pa1 = (float*)(ws + 4096);
    float* fb0 = (float*)(ws + 8192);
    float* fb1 = (float*)(ws + 8192 + (size_t)TOTAL * sizeof(float));

    void* args[] = {
        (void*)&inputs, (void*)&kern, (void*)&kernf, (void*)&latent,
        (void*)&fb0, (void*)&fb1, (void*)&pa0, (void*)&pa1
    };
    hipLaunchCooperativeKernel((void*)rl_persist, dim3(NBLKS), dim3(BLK),
                               args, 0, stream);
}

// Round 6
// 595.458 us; speedup vs baseline: 10.8350x; 10.8350x over previous
//
#include <hip/hip_runtime.h>

#define NB     4
#define H      512
#define W      512
#define ITERS  30
#define K      5             // iterations fused per dispatch
#define NGROUP 6             // 6 compute groups (+1 fixup dispatch)
#define TOLF   1e-05f
#define TOTAL  (NB*H*W*3)    // 3,145,728
#define BLK    256
#define NBLKS  1024          // 4 images x 16x16 tiles of 32x32
#define EXT    52            // 32 + 2*halo(10)
#define LRS    52
#define LPS    (52*52)       // 2704
#define RRS    50
#define RPS    (50*50)       // 2500
#define TBIG   1000000

__device__ __forceinline__ int refl(int v, int n) {
    if (v < 0)  return -v;
    if (v >= n) return 2 * n - 2 - v;
    return v;
}

// One dispatch = up to K fused RL iterations on a 32x32 tile with halo-10
// overlap. Symmetric Gaussian => reflection commutes with conv: mirror band
// is established once at staging and self-propagates (edge tiles read
// reflected `inputs`; everything else computes all extended positions).
//
// done-flag handling (exact scan semantics): optimistic execution +
// deterministic redundant scan of per-iteration partials. If the first
// firing iteration t* lies in the immediately previous group, recompute
// from that group's input buffer (3-buffer rotation keeps it intact) with
// m = t*-5(g-1)+1 iterations; older t* => passthrough. g==NGROUP is the
// fixup dispatch for firing inside the last group (else early-exit).
__global__ __launch_bounds__(BLK, 2) void rl_group(
    const float* __restrict__ inputs,
    const float* __restrict__ gk,
    const float* __restrict__ gkf,
    const float* __restrict__ src,       // latent at group start
    const float* __restrict__ src_prev,  // latent at PREVIOUS group start
    float* __restrict__ dst,
    float* __restrict__ part,            // [30][1024] iteration partials
    int g)
{
    __shared__ float lat[3 * LPS];       // 32448 B
    __shared__ float rbt[3 * RPS];       // 30000 B
    __shared__ float wred[4];
    __shared__ int   s_tstar;

    const int tid  = threadIdx.x;
    const int lane = tid & 63;
    const int wid  = tid >> 6;
    const int b    = blockIdx.x;
    const int n    = b >> 8;
    const int rtile= b & 255;
    const int ty0  = (rtile >> 4) << 5;
    const int tx0  = (rtile & 15) << 5;
    const bool xe0 = (tx0 == 0), xe1 = (tx0 + 32 == W);
    const bool ye0 = (ty0 == 0), ye1 = (ty0 + 32 == H);
    const bool edge = xe0 | xe1 | ye0 | ye1;
    const size_t nbase = (size_t)n * (H * W * 3);
    const float* inp_n = inputs + nbase;

    // ---- deterministic scan: first firing iteration among prior groups ----
    int tstar = TBIG;
    if (g > 0) {
        const int tmax = (g < NGROUP) ? 5 * g : ITERS;
        if (tid == 0) s_tstar = TBIG;
        __syncthreads();
        for (int t = wid; t < tmax; t += 4) {       // one wave per t (mod 4)
            double a = 0.0;
            for (int q = lane; q < NBLKS; q += 64)
                a += (double)part[t * NBLKS + q];
            #pragma unroll
            for (int off = 32; off; off >>= 1) a += __shfl_down(a, off, 64);
            if (lane == 0) {
                const float mean = (float)(a / (double)TOTAL);
                if (fabsf(1.0f - mean) < TOLF) atomicMin(&s_tstar, t);
            }
        }
        __syncthreads();
        tstar = s_tstar;
    }

    // ---- mode decision (block-uniform, identical across all blocks) ----
    int m;                     // iterations to run
    const float* lsrc;         // latent source buffer
    bool wr_part;
    if (g == 0) {
        m = K; lsrc = src; wr_part = true;
    } else if (tstar >= 5 * g) {                       // no firing yet
        if (g == NGROUP) return;                       // fixup: nothing to do
        m = K; lsrc = src; wr_part = true;
    } else if (tstar >= 5 * (g - 1)) {                 // fired in prev group
        m = tstar - 5 * (g - 1) + 1; lsrc = src_prev; wr_part = false;
    } else {                                           // frozen long ago
        if (g == NGROUP) return;                       // d_out already correct
        for (int p = tid; p < 1024; p += BLK) {        // passthrough copy
            const int i = p >> 5, j = p & 31;
            const size_t o = nbase + ((size_t)(ty0 + i) * W + (tx0 + j)) * 3;
            dst[o] = src[o]; dst[o + 1] = src[o + 1]; dst[o + 2] = src[o + 2];
        }
        return;
    }

    // ---- stage 52x52 latent tile (in-image part) ----
    const float* s_n = lsrc + nbase;
    for (int p = tid; p < EXT * EXT; p += BLK) {
        const int i = p / EXT, j = p - i * EXT;
        const int gy = ty0 - 10 + i, gx = tx0 - 10 + j;
        if ((unsigned)gy < (unsigned)H && (unsigned)gx < (unsigned)W) {
            const float* sp = s_n + ((size_t)gy * W + gx) * 3;
            const int l = i * LRS + j;
            lat[l]           = sp[0];
            lat[LPS + l]     = sp[1];
            lat[2 * LPS + l] = sp[2];
        }
    }
    __syncthreads();

    // ---- mirror fixups (once): columns, then rows (corners = double mirror) ----
    if (edge) {
        if (xe0) {
            for (int p = tid; p < 3 * EXT * 10; p += BLK) {
                const int c = p / (EXT * 10), rr = p - c * (EXT * 10);
                const int i = rr / 10, j = rr - i * 10;            // j in [0,10)
                lat[c * LPS + i * LRS + j] = lat[c * LPS + i * LRS + (20 - j)];
            }
        } else if (xe1) {
            for (int p = tid; p < 3 * EXT * 10; p += BLK) {
                const int c = p / (EXT * 10), rr = p - c * (EXT * 10);
                const int i = rr / 10, j2 = rr - i * 10;           // col 42+j2
                lat[c * LPS + i * LRS + 42 + j2] = lat[c * LPS + i * LRS + (40 - j2)];
            }
        }
        __syncthreads();
        if (ye0) {
            for (int p = tid; p < 3 * 10 * EXT; p += BLK) {
                const int c = p / (10 * EXT), rr = p - c * (10 * EXT);
                const int i = rr / EXT, j = rr - i * EXT;          // i in [0,10)
                lat[c * LPS + i * LRS + j] = lat[c * LPS + (20 - i) * LRS + j];
            }
        } else if (ye1) {
            for (int p = tid; p < 3 * 10 * EXT; p += BLK) {
                const int c = p / (10 * EXT), rr = p - c * (10 * EXT);
                const int i2 = rr / EXT, j = rr - i2 * EXT;        // row 42+i2
                lat[c * LPS + (42 + i2) * LRS + j] = lat[c * LPS + (40 - i2) * LRS + j];
            }
        }
        __syncthreads();
    }

    // ---- fused sub-iterations (compile-time region sizes via unroll) ----
    #pragma unroll
    for (int s = 0; s < K; ++s) {
        if (s >= m) break;
        // stage 1: rb on ext region [2s+1, 51-2s), size Rs (even), 2x2 blocks
        const int rb0 = 2 * s + 1;
        const int nbr = (50 - 4 * s) >> 1;
        if (!edge) {
            for (int p = tid; p < nbr * nbr; p += BLK) {
                const int bi = p / nbr, bj = p - bi * nbr;
                const int i0 = rb0 + 2 * bi, j0 = rb0 + 2 * bj;
                float v[3][4][4];
                #pragma unroll
                for (int c = 0; c < 3; ++c)
                    #pragma unroll
                    for (int rr = 0; rr < 4; ++rr)
                        #pragma unroll
                        for (int t2 = 0; t2 < 4; ++t2)
                            v[c][rr][t2] = lat[c * LPS + (i0 - 1 + rr) * LRS + (j0 - 1 + t2)];
                #pragma unroll
                for (int a = 0; a < 2; ++a) {
                    const float* ip = inp_n +
                        ((size_t)(ty0 - 10 + i0 + a) * W + (tx0 - 10 + j0)) * 3;
                    #pragma unroll
                    for (int bb = 0; bb < 2; ++bb)
                        #pragma unroll
                        for (int c = 0; c < 3; ++c) {
                            float acc = 0.f;
                            #pragma unroll
                            for (int dy = 0; dy < 3; ++dy)
                                #pragma unroll
                                for (int dx = 0; dx < 3; ++dx)
                                    acc = fmaf(v[c][a + dy][bb + dx],
                                               gk[(dy * 3 + dx) * 3 + c], acc);
                            rbt[c * RPS + (i0 + a - 1) * RRS + (j0 + bb - 1)] =
                                ip[bb * 3 + c] * __builtin_amdgcn_rcpf(acc);
                        }
                }
            }
        } else {
            for (int p = tid; p < nbr * nbr; p += BLK) {
                const int bi = p / nbr, bj = p - bi * nbr;
                const int i0 = rb0 + 2 * bi, j0 = rb0 + 2 * bj;
                float v[3][4][4];
                #pragma unroll
                for (int c = 0; c < 3; ++c)
                    #pragma unroll
                    for (int rr = 0; rr < 4; ++rr)
                        #pragma unroll
                        for (int t2 = 0; t2 < 4; ++t2)
                            v[c][rr][t2] = lat[c * LPS + (i0 - 1 + rr) * LRS + (j0 - 1 + t2)];
                #pragma unroll
                for (int a = 0; a < 2; ++a)
                    #pragma unroll
                    for (int bb = 0; bb < 2; ++bb) {
                        const int ry = refl(ty0 - 10 + i0 + a, H);
                        const int rx = refl(tx0 - 10 + j0 + bb, W);
                        const float* ip = inp_n + ((size_t)ry * W + rx) * 3;
                        #pragma unroll
                        for (int c = 0; c < 3; ++c) {
                            float acc = 0.f;
                            #pragma unroll
                            for (int dy = 0; dy < 3; ++dy)
                                #pragma unroll
                                for (int dx = 0; dx < 3; ++dx)
                                    acc = fmaf(v[c][a + dy][bb + dx],
                                               gk[(dy * 3 + dx) * 3 + c], acc);
                            rbt[c * RPS + (i0 + a - 1) * RRS + (j0 + bb - 1)] =
                                ip[c] * __builtin_amdgcn_rcpf(acc);
                        }
                    }
            }
        }
        __syncthreads();

        // stage 2: e = conv(rb, kf); lat *= e on ext region [2s+2, 50-2s)
        const int lb0 = 2 * s + 2;
        const int nbl = (48 - 4 * s) >> 1;
        float esum = 0.f;
        for (int p = tid; p < nbl * nbl; p += BLK) {
            const int bi = p / nbl, bj = p - bi * nbl;
            const int i0 = lb0 + 2 * bi, j0 = lb0 + 2 * bj;
            float v[3][4][4];
            #pragma unroll
            for (int c = 0; c < 3; ++c)
                #pragma unroll
                for (int rr = 0; rr < 4; ++rr)
                    #pragma unroll
                    for (int t2 = 0; t2 < 4; ++t2)
                        v[c][rr][t2] = rbt[c * RPS + (i0 - 2 + rr) * RRS + (j0 - 2 + t2)];
            #pragma unroll
            for (int a = 0; a < 2; ++a)
                #pragma unroll
                for (int bb = 0; bb < 2; ++bb) {
                    const bool in_int = ((unsigned)(i0 + a - 10) < 32u) &&
                                        ((unsigned)(j0 + bb - 10) < 32u);
                    #pragma unroll
                    for (int c = 0; c < 3; ++c) {
                        float e = 0.f;
                        #pragma unroll
                        for (int dy = 0; dy < 3; ++dy)
                            #pragma unroll
                            for (int dx = 0; dx < 3; ++dx)
                                e = fmaf(v[c][a + dy][bb + dx],
                                         gkf[(dy * 3 + dx) * 3 + c], e);
                        lat[c * LPS + (i0 + a) * LRS + (j0 + bb)] *= e;
                        if (in_int) esum += e;
                    }
                }
        }
        if (wr_part) {
            #pragma unroll
            for (int off = 32; off; off >>= 1) esum += __shfl_down(esum, off, 64);
            if (lane == 0) wred[wid] = esum;
        }
        __syncthreads();
        if (wr_part && tid == 0)
            part[(5 * g + s) * NBLKS + b] = wred[0] + wred[1] + wred[2] + wred[3];
        __syncthreads();
    }

    // ---- write interior [10,42)^2 to dst ----
    for (int p = tid; p < 1024; p += BLK) {
        const int i = p >> 5, j = p & 31;
        const int l = (i + 10) * LRS + (j + 10);
        float* op = dst + nbase + ((size_t)(ty0 + i) * W + (tx0 + j)) * 3;
        op[0] = lat[l];
        op[1] = lat[LPS + l];
        op[2] = lat[2 * LPS + l];
    }
}

extern "C" void kernel_launch(void* const* d_in, const int* in_sizes, int n_in,
                              void* d_out, int out_size, void* d_ws, size_t ws_size,
                              hipStream_t stream) {
    const float* inputs = (const float*)d_in[0];
    const float* gk     = (const float*)d_in[1];
    const float* gkf    = (const float*)d_in[2];
    float* out = (float*)d_out;

    // ws: [0 .. 120KB) iteration partials [30][1024] | buffer A | buffer B
    char* ws = (char*)d_ws;
    float* part = (float*)ws;
    float* A    = (float*)(ws + 131072);
    float* Bb   = (float*)(ws + 131072 + (size_t)TOTAL * sizeof(float));

    // 3-buffer rotation {A, B, out}: X[g] = latent at start of group g.
    // Recompute at dispatch g reads X[g-1] — distinct mod 3 from X[g] (read)
    // and X[g+1] (write), and untouched since dispatch g-1 wrote it.
    const float* X[7] = { inputs, A, Bb, out, A, Bb, out };

    for (int g = 0; g < 7; ++g) {
        const float* s  = X[(g == 6) ? 5 : g];
        const float* sp = X[(g == 0) ? 0 : g - 1];
        float*       d  = (float*)((g == 6) ? X[6] : X[g + 1]);
        rl_group<<<NBLKS, BLK, 0, stream>>>(inputs, gk, gkf, s, sp, d, part, g);
    }
}

// Round 7
// 567.102 us; speedup vs baseline: 11.3768x; 1.0500x over previous
//
#include <hip/hip_runtime.h>
#include <hip/hip_fp16.h>

#define NB     4
#define H      512
#define W      512
#define ITERS  30
#define K      5             // iterations fused per dispatch
#define NGROUP 6             // 6 compute groups (+1 fixup dispatch)
#define TOLF   1e-05f
#define TOTAL  (NB*H*W*3)    // 3,145,728
#define BLK    256
#define NBLKS  1024          // 4 images x 16x16 tiles of 32x32
#define EXT    52            // 32 + 2*halo(10)
#define LRS    52
#define LPS    (52*52)
#define RRS    50            // rb local row stride (halfs)
#define RPS    (50*50)
#define TBIG   1000000

__device__ __forceinline__ int refl(int v, int n) {
    if (v < 0)  return -v;
    if (v >= n) return 2 * n - 2 - v;
    return v;
}

// One dispatch = up to K fused RL iterations on a 32x32 tile with halo-10
// overlap. Symmetric Gaussian => reflection commutes with conv: mirror band
// established once at staging, self-propagates. done-flag: optimistic run +
// deterministic scan of per-iteration partials; firing in the previous group
// => recompute from that group's intact buffer (3-buffer rotation).
//
// R7: 1x2-pixel-pair mapping (lane-stride 8B float2 LDS reads, conflict-free)
// and fp16 rb tile (region-local origin, half2 accesses) -> 47.5 KB LDS,
// 3 blocks/CU.
__global__ __launch_bounds__(BLK, 3) void rl_group(
    const float* __restrict__ inputs,
    const float* __restrict__ gk,
    const float* __restrict__ gkf,
    const float* __restrict__ src,       // latent at group start
    const float* __restrict__ src_prev,  // latent at PREVIOUS group start
    float* __restrict__ dst,
    float* __restrict__ part,            // [30][1024] iteration partials
    int g)
{
    __shared__ float  lat[3 * LPS];      // 32448 B
    __shared__ __half rbt[3 * RPS];      // 15000 B
    __shared__ float  wred[4];
    __shared__ int    s_tstar;

    const int tid  = threadIdx.x;
    const int lane = tid & 63;
    const int wid  = tid >> 6;
    const int b    = blockIdx.x;
    const int n    = b >> 8;
    const int rtile= b & 255;
    const int ty0  = (rtile >> 4) << 5;
    const int tx0  = (rtile & 15) << 5;
    const bool xe0 = (tx0 == 0), xe1 = (tx0 + 32 == W);
    const bool ye0 = (ty0 == 0), ye1 = (ty0 + 32 == H);
    const bool edge = xe0 | xe1 | ye0 | ye1;
    const size_t nbase = (size_t)n * (H * W * 3);
    const float* inp_n = inputs + nbase;

    // ---- deterministic scan: first firing iteration among prior groups ----
    int tstar = TBIG;
    if (g > 0) {
        const int tmax = (g < NGROUP) ? 5 * g : ITERS;
        if (tid == 0) s_tstar = TBIG;
        __syncthreads();
        for (int t = wid; t < tmax; t += 4) {
            double a = 0.0;
            for (int q = lane; q < NBLKS; q += 64)
                a += (double)part[t * NBLKS + q];
            #pragma unroll
            for (int off = 32; off; off >>= 1) a += __shfl_down(a, off, 64);
            if (lane == 0) {
                const float mean = (float)(a / (double)TOTAL);
                if (fabsf(1.0f - mean) < TOLF) atomicMin(&s_tstar, t);
            }
        }
        __syncthreads();
        tstar = s_tstar;
    }

    // ---- mode decision (block-uniform, identical across all blocks) ----
    int m;
    const float* lsrc;
    bool wr_part;
    if (g == 0) {
        m = K; lsrc = src; wr_part = true;
    } else if (tstar >= 5 * g) {                       // no firing yet
        if (g == NGROUP) return;
        m = K; lsrc = src; wr_part = true;
    } else if (tstar >= 5 * (g - 1)) {                 // fired in prev group
        m = tstar - 5 * (g - 1) + 1; lsrc = src_prev; wr_part = false;
    } else {                                           // frozen long ago
        if (g == NGROUP) return;
        for (int p = tid; p < 1024; p += BLK) {
            const int i = p >> 5, j = p & 31;
            const size_t o = nbase + ((size_t)(ty0 + i) * W + (tx0 + j)) * 3;
            dst[o] = src[o]; dst[o + 1] = src[o + 1]; dst[o + 2] = src[o + 2];
        }
        return;
    }

    // ---- stage 52x52 latent tile (in-image part) ----
    const float* s_n = lsrc + nbase;
    for (int p = tid; p < EXT * EXT; p += BLK) {
        const int i = p / EXT, j = p - i * EXT;
        const int gy = ty0 - 10 + i, gx = tx0 - 10 + j;
        if ((unsigned)gy < (unsigned)H && (unsigned)gx < (unsigned)W) {
            const float* sp = s_n + ((size_t)gy * W + gx) * 3;
            const int l = i * LRS + j;
            lat[l]           = sp[0];
            lat[LPS + l]     = sp[1];
            lat[2 * LPS + l] = sp[2];
        }
    }
    __syncthreads();

    // ---- mirror fixups (once): columns, then rows ----
    if (edge) {
        if (xe0) {
            for (int p = tid; p < 3 * EXT * 10; p += BLK) {
                const int c = p / (EXT * 10), rr = p - c * (EXT * 10);
                const int i = rr / 10, j = rr - i * 10;
                lat[c * LPS + i * LRS + j] = lat[c * LPS + i * LRS + (20 - j)];
            }
        } else if (xe1) {
            for (int p = tid; p < 3 * EXT * 10; p += BLK) {
                const int c = p / (EXT * 10), rr = p - c * (EXT * 10);
                const int i = rr / 10, j2 = rr - i * 10;
                lat[c * LPS + i * LRS + 42 + j2] = lat[c * LPS + i * LRS + (40 - j2)];
            }
        }
        __syncthreads();
        if (ye0) {
            for (int p = tid; p < 3 * 10 * EXT; p += BLK) {
                const int c = p / (10 * EXT), rr = p - c * (10 * EXT);
                const int i = rr / EXT, j = rr - i * EXT;
                lat[c * LPS + i * LRS + j] = lat[c * LPS + (20 - i) * LRS + j];
            }
        } else if (ye1) {
            for (int p = tid; p < 3 * 10 * EXT; p += BLK) {
                const int c = p / (10 * EXT), rr = p - c * (10 * EXT);
                const int i2 = rr / EXT, j = rr - i2 * EXT;
                lat[c * LPS + (42 + i2) * LRS + j] = lat[c * LPS + (40 - i2) * LRS + j];
            }
        }
        __syncthreads();
    }

    // ---- fused sub-iterations ----
    #pragma unroll
    for (int s = 0; s < K; ++s) {
        if (s >= m) break;
        const int rb0 = 2 * s + 1;          // rb region origin (ext), odd
        const int Rs  = 50 - 4 * s;         // rb region side (even)
        const int jpr = Rs >> 1;

        // stage 1: rb = inp * rcp(conv(lat, k)) on [rb0, rb0+Rs)^2
        // 1x2 pixel pairs; lat cols je-1..je+2 = two aligned float2 reads.
        if (!edge) {
            for (int p = tid; p < Rs * jpr; p += BLK) {
                const int i  = p / jpr;
                const int k2 = p - i * jpr;
                const int ie = rb0 + i;
                const int je = rb0 + 2 * k2;          // odd
                const float* ip = inp_n +
                    ((size_t)(ty0 - 10 + ie) * W + (tx0 - 10 + je)) * 3;
                #pragma unroll
                for (int c = 0; c < 3; ++c) {
                    float a0 = 0.f, a1 = 0.f;
                    #pragma unroll
                    for (int dy = 0; dy < 3; ++dy) {
                        const float2* Lr = (const float2*)
                            &lat[c * LPS + (ie - 1 + dy) * LRS + (je - 1)];
                        const float2 A = Lr[0], Bv = Lr[1];
                        const float w0 = gk[(dy * 3 + 0) * 3 + c];
                        const float w1 = gk[(dy * 3 + 1) * 3 + c];
                        const float w2 = gk[(dy * 3 + 2) * 3 + c];
                        a0 = fmaf(A.x, w0, fmaf(A.y, w1, fmaf(Bv.x, w2, a0)));
                        a1 = fmaf(A.y, w0, fmaf(Bv.x, w1, fmaf(Bv.y, w2, a1)));
                    }
                    const float r0 = ip[c]     * __builtin_amdgcn_rcpf(a0);
                    const float r1 = ip[3 + c] * __builtin_amdgcn_rcpf(a1);
                    *(__half2*)&rbt[c * RPS + i * RRS + 2 * k2] =
                        __floats2half2_rn(r0, r1);
                }
            }
        } else {
            for (int p = tid; p < Rs * jpr; p += BLK) {
                const int i  = p / jpr;
                const int k2 = p - i * jpr;
                const int ie = rb0 + i;
                const int je = rb0 + 2 * k2;
                const int ry  = refl(ty0 - 10 + ie, H);
                const int rx0 = refl(tx0 - 10 + je, W);
                const int rx1 = refl(tx0 - 10 + je + 1, W);
                const float* ipa = inp_n + ((size_t)ry * W + rx0) * 3;
                const float* ipb = inp_n + ((size_t)ry * W + rx1) * 3;
                #pragma unroll
                for (int c = 0; c < 3; ++c) {
                    float a0 = 0.f, a1 = 0.f;
                    #pragma unroll
                    for (int dy = 0; dy < 3; ++dy) {
                        const float2* Lr = (const float2*)
                            &lat[c * LPS + (ie - 1 + dy) * LRS + (je - 1)];
                        const float2 A = Lr[0], Bv = Lr[1];
                        const float w0 = gk[(dy * 3 + 0) * 3 + c];
                        const float w1 = gk[(dy * 3 + 1) * 3 + c];
                        const float w2 = gk[(dy * 3 + 2) * 3 + c];
                        a0 = fmaf(A.x, w0, fmaf(A.y, w1, fmaf(Bv.x, w2, a0)));
                        a1 = fmaf(A.y, w0, fmaf(Bv.x, w1, fmaf(Bv.y, w2, a1)));
                    }
                    const float r0 = ipa[c] * __builtin_amdgcn_rcpf(a0);
                    const float r1 = ipb[c] * __builtin_amdgcn_rcpf(a1);
                    *(__half2*)&rbt[c * RPS + i * RRS + 2 * k2] =
                        __floats2half2_rn(r0, r1);
                }
            }
        }
        __syncthreads();

        // stage 2: e = conv(rb, kf); lat *= e on [lb0, lb0+Ls)^2
        const int lb0  = 2 * s + 2;         // even
        const int Ls   = 48 - 4 * s;
        const int jpr2 = Ls >> 1;
        float esum = 0.f;
        for (int p = tid; p < Ls * jpr2; p += BLK) {
            const int i  = p / jpr2;
            const int k2 = p - i * jpr2;
            const int ie = lb0 + i;
            const int je = lb0 + 2 * k2;              // even
            const int il = ie - rb0;                  // rb local center row
            const int jl = 2 * k2;                    // rb local col base (even)
            const bool iok  = ((unsigned)(ie - 10) < 32u);
            const bool j0ok = ((unsigned)(je - 10) < 32u);
            const bool j1ok = ((unsigned)(je + 1 - 10) < 32u);
            #pragma unroll
            for (int c = 0; c < 3; ++c) {
                float e0 = 0.f, e1 = 0.f;
                #pragma unroll
                for (int dy = 0; dy < 3; ++dy) {
                    const __half2* Rr = (const __half2*)
                        &rbt[c * RPS + (il - 1 + dy) * RRS + jl];
                    const float2 A  = __half22float2(Rr[0]);
                    const float2 Bv = __half22float2(Rr[1]);
                    const float w0 = gkf[(dy * 3 + 0) * 3 + c];
                    const float w1 = gkf[(dy * 3 + 1) * 3 + c];
                    const float w2 = gkf[(dy * 3 + 2) * 3 + c];
                    e0 = fmaf(A.x, w0, fmaf(A.y, w1, fmaf(Bv.x, w2, e0)));
                    e1 = fmaf(A.y, w0, fmaf(Bv.x, w1, fmaf(Bv.y, w2, e1)));
                }
                float2* Lp = (float2*)&lat[c * LPS + ie * LRS + je];
                float2 lv = *Lp;
                lv.x *= e0; lv.y *= e1;
                *Lp = lv;
                esum += (iok & j0ok) ? e0 : 0.f;
                esum += (iok & j1ok) ? e1 : 0.f;
            }
        }
        if (wr_part) {
            #pragma unroll
            for (int off = 32; off; off >>= 1) esum += __shfl_down(esum, off, 64);
            if (lane == 0) wred[wid] = esum;
        }
        __syncthreads();
        if (wr_part && tid == 0)
            part[(5 * g + s) * NBLKS + b] = wred[0] + wred[1] + wred[2] + wred[3];
        __syncthreads();
    }

    // ---- write interior [10,42)^2 to dst ----
    for (int p = tid; p < 1024; p += BLK) {
        const int i = p >> 5, j = p & 31;
        const int l = (i + 10) * LRS + (j + 10);
        float* op = dst + nbase + ((size_t)(ty0 + i) * W + (tx0 + j)) * 3;
        op[0] = lat[l];
        op[1] = lat[LPS + l];
        op[2] = lat[2 * LPS + l];
    }
}

extern "C" void kernel_launch(void* const* d_in, const int* in_sizes, int n_in,
                              void* d_out, int out_size, void* d_ws, size_t ws_size,
                              hipStream_t stream) {
    const float* inputs = (const float*)d_in[0];
    const float* gk     = (const float*)d_in[1];
    const float* gkf    = (const float*)d_in[2];
    float* out = (float*)d_out;

    // ws: [0 .. 128KB) iteration partials [30][1024] | buffer A | buffer B
    char* ws = (char*)d_ws;
    float* part = (float*)ws;
    float* A    = (float*)(ws + 131072);
    float* Bb   = (float*)(ws + 131072 + (size_t)TOTAL * sizeof(float));

    // 3-buffer rotation {A, B, out}: X[g] = latent at start of group g.
    const float* X[7] = { inputs, A, Bb, out, A, Bb, out };

    for (int g = 0; g < 7; ++g) {
        const float* s  = X[(g == 6) ? 5 : g];
        const float* sp = X[(g == 0) ? 0 : g - 1];
        float*       d  = (float*)((g == 6) ? X[6] : X[g + 1]);
        rl_group<<<NBLKS, BLK, 0, stream>>>(inputs, gk, gkf, s, sp, d, part, g);
    }
}

// Round 8
// 517.750 us; speedup vs baseline: 12.4612x; 1.0953x over previous
//
#include <hip/hip_runtime.h>
#include <hip/hip_fp16.h>

#define NB     4
#define H      512
#define W      512
#define ITERS  30
#define K      4             // max iterations fused per dispatch
#define TOLF   1e-05f
#define TOTAL  (NB*H*W*3)    // 3,145,728
#define BLK    256
#define NBLKS  1024          // 4 images x 16x16 tiles of 32x32
#define HALO   8
#define EXT    48            // 32 + 2*HALO
#define LRS    48
#define LPS    (48*48)       // 2304
#define RRS    46            // rb local row stride (halfs)
#define RPS    (46*46)       // 2116
#define TBIG   1000000

__device__ __forceinline__ int refl(int v, int n) {
    if (v < 0)  return -v;
    if (v >= n) return 2 * n - 2 - v;
    return v;
}

// One dispatch = up to K=4 fused RL iterations on a 32x32 tile, halo-8
// overlap. 40.3 KB LDS -> 4 blocks/CU; 1024 blocks = exactly one residency
// round. Symmetric Gaussian => reflection commutes with conv (mirror band
// staged once, self-propagates). done-flag: optimistic run + deterministic
// scan of per-iteration partials; firing in the previous group => recompute
// from that group's intact source (period-3 buffer schedule).
__global__ __launch_bounds__(BLK, 4) void rl_group(
    const float* __restrict__ inputs,
    const float* __restrict__ gk,
    const float* __restrict__ gkf,
    const float* __restrict__ src,       // latent at group start
    const float* __restrict__ src_prev,  // latent at PREVIOUS group start
    float* __restrict__ dst,
    float* __restrict__ part,            // [30][1024] iteration partials
    int g)                               // 0..7 compute, 8 fixup
{
    __shared__ float  lat[3 * LPS];      // 27648 B
    __shared__ __half rbt[3 * RPS];      // 12696 B
    __shared__ float  wred[4];
    __shared__ int    s_tstar;

    const int tid  = threadIdx.x;
    const int lane = tid & 63;
    const int wid  = tid >> 6;
    const int b    = blockIdx.x;
    const int n    = b >> 8;
    const int rtile= b & 255;
    const int ty0  = (rtile >> 4) << 5;
    const int tx0  = (rtile & 15) << 5;
    const bool xe0 = (tx0 == 0), xe1 = (tx0 + 32 == W);
    const bool ye0 = (ty0 == 0), ye1 = (ty0 + 32 == H);
    const bool edge = xe0 | xe1 | ye0 | ye1;
    const size_t nbase = (size_t)n * (H * W * 3);
    const float* inp_n = inputs + nbase;

    const int base      = (4 * g < ITERS) ? 4 * g : ITERS;   // this group's first iter
    const int prev_base = (g > 0) ? 4 * (g - 1) : 0;

    // ---- deterministic scan: first firing iteration among prior groups ----
    int tstar = TBIG;
    if (g > 0) {
        const int tmax = base;           // iterations completed before this group
        if (tid == 0) s_tstar = TBIG;
        __syncthreads();
        for (int t = wid; t < tmax; t += 4) {
            double a = 0.0;
            for (int q = lane; q < NBLKS; q += 64)
                a += (double)part[t * NBLKS + q];
            #pragma unroll
            for (int off = 32; off; off >>= 1) a += __shfl_down(a, off, 64);
            if (lane == 0) {
                const float mean = (float)(a / (double)TOTAL);
                if (fabsf(1.0f - mean) < TOLF) atomicMin(&s_tstar, t);
            }
        }
        __syncthreads();
        tstar = s_tstar;
    }

    // ---- mode decision (block-uniform, identical across all blocks) ----
    int m;
    const float* lsrc;
    bool wr_part;
    if (g == 0) {
        m = K; lsrc = src; wr_part = true;
    } else if (tstar >= base) {                        // no firing yet
        if (g == 8) return;                            // fixup: out already final
        m = (ITERS - base < K) ? (ITERS - base) : K;
        lsrc = src; wr_part = true;
    } else if (tstar >= prev_base) {                   // fired in prev group
        m = tstar - prev_base + 1; lsrc = src_prev; wr_part = false;
    } else {                                           // frozen long ago
        if (g == 8) return;
        for (int p = tid; p < 1024; p += BLK) {        // passthrough copy
            const int i = p >> 5, j = p & 31;
            const size_t o = nbase + ((size_t)(ty0 + i) * W + (tx0 + j)) * 3;
            dst[o] = src[o]; dst[o + 1] = src[o + 1]; dst[o + 2] = src[o + 2];
        }
        return;
    }

    // ---- stage 48x48 latent tile (in-image part) ----
    const float* s_n = lsrc + nbase;
    for (int p = tid; p < EXT * EXT; p += BLK) {
        const int i = p / EXT, j = p - i * EXT;
        const int gy = ty0 - HALO + i, gx = tx0 - HALO + j;
        if ((unsigned)gy < (unsigned)H && (unsigned)gx < (unsigned)W) {
            const float* sp = s_n + ((size_t)gy * W + gx) * 3;
            const int l = i * LRS + j;
            lat[l]           = sp[0];
            lat[LPS + l]     = sp[1];
            lat[2 * LPS + l] = sp[2];
        }
    }
    __syncthreads();

    // ---- mirror fixups (once): columns, then rows ----
    if (edge) {
        if (xe0) {
            for (int p = tid; p < 3 * EXT * HALO; p += BLK) {
                const int c = p / (EXT * HALO), rr = p - c * (EXT * HALO);
                const int i = rr / HALO, j = rr - i * HALO;       // j in [0,8)
                lat[c * LPS + i * LRS + j] = lat[c * LPS + i * LRS + (16 - j)];
            }
        } else if (xe1) {
            for (int p = tid; p < 3 * EXT * HALO; p += BLK) {
                const int c = p / (EXT * HALO), rr = p - c * (EXT * HALO);
                const int i = rr / HALO, j2 = rr - i * HALO;      // col 40+j2
                lat[c * LPS + i * LRS + 40 + j2] = lat[c * LPS + i * LRS + (38 - j2)];
            }
        }
        __syncthreads();
        if (ye0) {
            for (int p = tid; p < 3 * HALO * EXT; p += BLK) {
                const int c = p / (HALO * EXT), rr = p - c * (HALO * EXT);
                const int i = rr / EXT, j = rr - i * EXT;         // i in [0,8)
                lat[c * LPS + i * LRS + j] = lat[c * LPS + (16 - i) * LRS + j];
            }
        } else if (ye1) {
            for (int p = tid; p < 3 * HALO * EXT; p += BLK) {
                const int c = p / (HALO * EXT), rr = p - c * (HALO * EXT);
                const int i2 = rr / EXT, j = rr - i2 * EXT;       // row 40+i2
                lat[c * LPS + (40 + i2) * LRS + j] = lat[c * LPS + (38 - i2) * LRS + j];
            }
        }
        __syncthreads();
    }

    // ---- fused sub-iterations (2 barriers each) ----
    #pragma unroll
    for (int s = 0; s < K; ++s) {
        if (s >= m) break;
        const int rb0 = 2 * s + 1;          // rb region origin (ext), odd
        const int Rs  = 46 - 4 * s;         // rb region side (even)
        const int jpr = Rs >> 1;

        // stage 1: rb = inp * rcp(conv(lat, k)) on [rb0, rb0+Rs)^2, 1x2 pairs
        if (!edge) {
            for (int p = tid; p < Rs * jpr; p += BLK) {
                const int i  = p / jpr;
                const int k2 = p - i * jpr;
                const int ie = rb0 + i;
                const int je = rb0 + 2 * k2;          // odd
                const float* ip = inp_n +
                    ((size_t)(ty0 - HALO + ie) * W + (tx0 - HALO + je)) * 3;
                #pragma unroll
                for (int c = 0; c < 3; ++c) {
                    float a0 = 0.f, a1 = 0.f;
                    #pragma unroll
                    for (int dy = 0; dy < 3; ++dy) {
                        const float2* Lr = (const float2*)
                            &lat[c * LPS + (ie - 1 + dy) * LRS + (je - 1)];
                        const float2 A = Lr[0], Bv = Lr[1];
                        const float w0 = gk[(dy * 3 + 0) * 3 + c];
                        const float w1 = gk[(dy * 3 + 1) * 3 + c];
                        const float w2 = gk[(dy * 3 + 2) * 3 + c];
                        a0 = fmaf(A.x, w0, fmaf(A.y, w1, fmaf(Bv.x, w2, a0)));
                        a1 = fmaf(A.y, w0, fmaf(Bv.x, w1, fmaf(Bv.y, w2, a1)));
                    }
                    const float r0 = ip[c]     * __builtin_amdgcn_rcpf(a0);
                    const float r1 = ip[3 + c] * __builtin_amdgcn_rcpf(a1);
                    *(__half2*)&rbt[c * RPS + i * RRS + 2 * k2] =
                        __floats2half2_rn(r0, r1);
                }
            }
        } else {
            for (int p = tid; p < Rs * jpr; p += BLK) {
                const int i  = p / jpr;
                const int k2 = p - i * jpr;
                const int ie = rb0 + i;
                const int je = rb0 + 2 * k2;
                const int ry  = refl(ty0 - HALO + ie, H);
                const int rx0 = refl(tx0 - HALO + je, W);
                const int rx1 = refl(tx0 - HALO + je + 1, W);
                const float* ipa = inp_n + ((size_t)ry * W + rx0) * 3;
                const float* ipb = inp_n + ((size_t)ry * W + rx1) * 3;
                #pragma unroll
                for (int c = 0; c < 3; ++c) {
                    float a0 = 0.f, a1 = 0.f;
                    #pragma unroll
                    for (int dy = 0; dy < 3; ++dy) {
                        const float2* Lr = (const float2*)
                            &lat[c * LPS + (ie - 1 + dy) * LRS + (je - 1)];
                        const float2 A = Lr[0], Bv = Lr[1];
                        const float w0 = gk[(dy * 3 + 0) * 3 + c];
                        const float w1 = gk[(dy * 3 + 1) * 3 + c];
                        const float w2 = gk[(dy * 3 + 2) * 3 + c];
                        a0 = fmaf(A.x, w0, fmaf(A.y, w1, fmaf(Bv.x, w2, a0)));
                        a1 = fmaf(A.y, w0, fmaf(Bv.x, w1, fmaf(Bv.y, w2, a1)));
                    }
                    const float r0 = ipa[c] * __builtin_amdgcn_rcpf(a0);
                    const float r1 = ipb[c] * __builtin_amdgcn_rcpf(a1);
                    *(__half2*)&rbt[c * RPS + i * RRS + 2 * k2] =
                        __floats2half2_rn(r0, r1);
                }
            }
        }
        __syncthreads();

        // stage 2: e = conv(rb, kf); lat *= e on [lb0, lb0+Ls)^2
        const int lb0  = 2 * s + 2;         // even
        const int Ls   = 44 - 4 * s;
        const int jpr2 = Ls >> 1;
        float esum = 0.f;
        for (int p = tid; p < Ls * jpr2; p += BLK) {
            const int i  = p / jpr2;
            const int k2 = p - i * jpr2;
            const int ie = lb0 + i;
            const int je = lb0 + 2 * k2;              // even
            const int il = ie - rb0;                  // rb local center row
            const int jl = 2 * k2;                    // rb local col base (even)
            const bool iok  = ((unsigned)(ie - HALO) < 32u);
            const bool j0ok = ((unsigned)(je - HALO) < 32u);
            const bool j1ok = ((unsigned)(je + 1 - HALO) < 32u);
            #pragma unroll
            for (int c = 0; c < 3; ++c) {
                float e0 = 0.f, e1 = 0.f;
                #pragma unroll
                for (int dy = 0; dy < 3; ++dy) {
                    const __half2* Rr = (const __half2*)
                        &rbt[c * RPS + (il - 1 + dy) * RRS + jl];
                    const float2 A  = __half22float2(Rr[0]);
                    const float2 Bv = __half22float2(Rr[1]);
                    const float w0 = gkf[(dy * 3 + 0) * 3 + c];
                    const float w1 = gkf[(dy * 3 + 1) * 3 + c];
                    const float w2 = gkf[(dy * 3 + 2) * 3 + c];
                    e0 = fmaf(A.x, w0, fmaf(A.y, w1, fmaf(Bv.x, w2, e0)));
                    e1 = fmaf(A.y, w0, fmaf(Bv.x, w1, fmaf(Bv.y, w2, e1)));
                }
                float2* Lp = (float2*)&lat[c * LPS + ie * LRS + je];
                float2 lv = *Lp;
                lv.x *= e0; lv.y *= e1;
                *Lp = lv;
                esum += (iok & j0ok) ? e0 : 0.f;
                esum += (iok & j1ok) ? e1 : 0.f;
            }
        }
        if (wr_part) {
            #pragma unroll
            for (int off = 32; off; off >>= 1) esum += __shfl_down(esum, off, 64);
            if (lane == 0) wred[wid] = esum;
        }
        __syncthreads();
        if (wr_part && tid == 0)
            part[(base + s) * NBLKS + b] = wred[0] + wred[1] + wred[2] + wred[3];
        // no trailing barrier: wred is next written only after the next
        // stage1->stage2 __syncthreads.
    }

    // ---- write interior [8,40)^2 to dst ----
    for (int p = tid; p < 1024; p += BLK) {
        const int i = p >> 5, j = p & 31;
        const int l = (i + HALO) * LRS + (j + HALO);
        float* op = dst + nbase + ((size_t)(ty0 + i) * W + (tx0 + j)) * 3;
        op[0] = lat[l];
        op[1] = lat[LPS + l];
        op[2] = lat[2 * LPS + l];
    }
}

extern "C" void kernel_launch(void* const* d_in, const int* in_sizes, int n_in,
                              void* d_out, int out_size, void* d_ws, size_t ws_size,
                              hipStream_t stream) {
    const float* inputs = (const float*)d_in[0];
    const float* gk     = (const float*)d_in[1];
    const float* gkf    = (const float*)d_in[2];
    float* out = (float*)d_out;

    // ws: [0 .. 128KB) iteration partials [30][1024] | buffer A | buffer B
    char* ws = (char*)d_ws;
    float* part = (float*)ws;
    float* A    = (float*)(ws + 131072);
    float* Bb   = (float*)(ws + 131072 + (size_t)TOTAL * sizeof(float));

    // period-3 schedule; X[g] = latent at start of group g. X[8] = out.
    // Guarantees: X[g]!=X[g+1], X[g-1]!=X[g+1] (recompute src intact & != dst).
    const float* X[9] = { inputs, A, out, Bb, A, out, Bb, A, out };

    for (int g = 0; g < 9; ++g) {
        const float* s  = X[(g == 8) ? 7 : g];
        const float* sp = X[(g == 0) ? 0 : g - 1];
        float*       d  = (float*)((g == 8) ? X[8] : X[g + 1]);
        rl_group<<<NBLKS, BLK, 0, stream>>>(inputs, gk, gkf, s, sp, d, part, g);
    }
}

// Round 10
// 509.338 us; speedup vs baseline: 12.6670x; 1.0165x over previous
//
#include <hip/hip_runtime.h>
#include <hip/hip_fp16.h>

#define NB     4
#define H      512
#define W      512
#define ITERS  30
#define K      4             // max iterations fused per dispatch
#define TOLF   1e-05f
#define TOTAL  (NB*H*W*3)    // 3,145,728
#define BLK    256
#define NBLKS  1024          // 4 images x 16x16 tiles of 32x32
#define HALO   8
#define EXT    48            // 32 + 2*HALO
#define LRS    48
#define LPS    (48*48)       // 2304
#define RRS    46            // rbt row stride (ext-1 coords, halfs)
#define RPS    (46*46)       // 2116
#define NP1    1058          // stage-1 pairs: 46 rows x 23 pair-cols
#define NP2    968           // stage-2 pairs: 44 rows x 22 pair-cols
#define TBIG   1000000

__device__ __forceinline__ int refl(int v, int n) {
    if (v < 0)  return -v;
    if (v >= n) return 2 * n - 2 - v;
    return v;
}

// One dispatch = up to K=4 fused RL iterations on a 32x32 tile, halo-8.
// Fixed thread->pair mapping across sub-iterations; `inputs` register-cached
// at dispatch start; all LDS offsets precomputed, s-invariant (rbt in ext-1
// coords: rb at ext (y,x) lives at rbt[(y-1)*RRS + (x-1)]). Symmetric
// Gaussian => reflection commutes with conv (mirror band staged once).
// done-flag: optimistic run + deterministic partials scan; firing in the
// previous group => recompute from that group's intact source (period-3
// buffer schedule).
__global__ __launch_bounds__(BLK, 4) void rl_group(
    const float* __restrict__ inputs,
    const float* __restrict__ gk,
    const float* __restrict__ gkf,
    const float* __restrict__ src,       // latent at group start
    const float* __restrict__ src_prev,  // latent at PREVIOUS group start
    float* __restrict__ dst,
    float* __restrict__ part,            // [30][1024] iteration partials
    int g)                               // 0..7 compute, 8 fixup
{
    __shared__ float  lat[3 * LPS];      // 27648 B
    __shared__ __half rbt[3 * RPS];      // 12696 B
    __shared__ float  wred[4];
    __shared__ int    s_tstar;

    const int tid  = threadIdx.x;
    const int lane = tid & 63;
    const int wid  = tid >> 6;
    const int b    = blockIdx.x;
    const int n    = b >> 8;
    const int rtile= b & 255;
    const int ty0  = (rtile >> 4) << 5;
    const int tx0  = (rtile & 15) << 5;
    const bool xe0 = (tx0 == 0), xe1 = (tx0 + 32 == W);
    const bool ye0 = (ty0 == 0), ye1 = (ty0 + 32 == H);
    const bool edge = xe0 | xe1 | ye0 | ye1;
    const size_t nbase = (size_t)n * (H * W * 3);
    const float* inp_n = inputs + nbase;

    const int base      = (4 * g < ITERS) ? 4 * g : ITERS;
    const int prev_base = (g > 0) ? 4 * (g - 1) : 0;

    // ---- deterministic scan: first firing iteration among prior groups ----
    int tstar = TBIG;
    if (g > 0) {
        const int tmax = base;
        if (tid == 0) s_tstar = TBIG;
        __syncthreads();
        for (int t = wid; t < tmax; t += 4) {
            double a = 0.0;
            for (int q = lane; q < NBLKS; q += 64)
                a += (double)part[t * NBLKS + q];
            #pragma unroll
            for (int off = 32; off; off >>= 1) a += __shfl_down(a, off, 64);
            if (lane == 0) {
                const float mean = (float)(a / (double)TOTAL);
                if (fabsf(1.0f - mean) < TOLF) atomicMin(&s_tstar, t);
            }
        }
        __syncthreads();
        tstar = s_tstar;
    }

    // ---- mode decision (block-uniform, identical across all blocks) ----
    int m;
    const float* lsrc;
    bool wr_part;
    if (g == 0) {
        m = K; lsrc = src; wr_part = true;
    } else if (tstar >= base) {
        if (g == 8) return;
        m = (ITERS - base < K) ? (ITERS - base) : K;
        lsrc = src; wr_part = true;
    } else if (tstar >= prev_base) {
        m = tstar - prev_base + 1; lsrc = src_prev; wr_part = false;
    } else {
        if (g == 8) return;
        for (int p = tid; p < 1024; p += BLK) {
            const int i = p >> 5, j = p & 31;
            const size_t o = nbase + ((size_t)(ty0 + i) * W + (tx0 + j)) * 3;
            dst[o] = src[o]; dst[o + 1] = src[o + 1]; dst[o + 2] = src[o + 2];
        }
        return;
    }

    // ---- fixed stage-1 pair metadata + register-cached inputs ----
    // pair q: i = q/23 + 1 in [1,47), j = 2*(q%23) + 1 (odd)
    int   s1lat[5], s1rb[5], s1mrg[5];
    float ir[5][6];                      // [pair][c] px0, [pair][3+c] px1
    #pragma unroll
    for (int up = 0; up < 5; ++up) {
        const int q = tid + up * BLK;
        s1mrg[up] = -1;
        if (q < NP1) {
            const int i = q / 23 + 1;
            const int j = 2 * (q - (i - 1) * 23) + 1;
            s1lat[up] = i * LRS + j;
            s1rb[up]  = (i - 1) * RRS + (j - 1);
            int mg = i - 1;
            mg = min(mg, 46 - i); mg = min(mg, j - 1); mg = min(mg, 45 - j);
            s1mrg[up] = mg;
            const int ry  = refl(ty0 - HALO + i, H);
            const int rx0 = refl(tx0 - HALO + j, W);
            const int rx1 = refl(tx0 - HALO + j + 1, W);
            const float* pa = inp_n + ((size_t)ry * W + rx0) * 3;
            const float* pb = inp_n + ((size_t)ry * W + rx1) * 3;
            #pragma unroll
            for (int c = 0; c < 3; ++c) { ir[up][c] = pa[c]; ir[up][3 + c] = pb[c]; }
        }
    }

    // ---- fixed stage-2 pair metadata ----
    // pair q: i = q/22 + 2 in [2,46), j = 2*(q%22) + 2 (even)
    int s2lat[4], s2rb[4], s2mrg[4], s2msk[4];
    #pragma unroll
    for (int up = 0; up < 4; ++up) {
        const int q = tid + up * BLK;
        s2mrg[up] = -1; s2msk[up] = 0;
        if (q < NP2) {
            const int i = q / 22 + 2;
            const int j = 2 * (q - (i - 2) * 22) + 2;
            s2lat[up] = i * LRS + j;
            s2rb[up]  = (i - 2) * RRS + (j - 2);
            int mg = i - 2;
            mg = min(mg, 45 - i); mg = min(mg, j - 2); mg = min(mg, 44 - j);
            s2mrg[up] = mg;
            const bool iok = ((unsigned)(i - HALO) < 32u);
            s2msk[up] = (iok && ((unsigned)(j - HALO) < 32u) ? 1 : 0)
                      | (iok && ((unsigned)(j + 1 - HALO) < 32u) ? 2 : 0);
        }
    }

    // ---- stage 48x48 latent tile (in-image part) ----
    const float* s_n = lsrc + nbase;
    for (int p = tid; p < EXT * EXT; p += BLK) {
        const int i = p / EXT, j = p - i * EXT;
        const int gy = ty0 - HALO + i, gx = tx0 - HALO + j;
        if ((unsigned)gy < (unsigned)H && (unsigned)gx < (unsigned)W) {
            const float* sp = s_n + ((size_t)gy * W + gx) * 3;
            const int l = i * LRS + j;
            lat[l]           = sp[0];
            lat[LPS + l]     = sp[1];
            lat[2 * LPS + l] = sp[2];
        }
    }
    __syncthreads();

    // ---- mirror fixups (once): columns, then rows ----
    if (edge) {
        if (xe0) {
            for (int p = tid; p < 3 * EXT * HALO; p += BLK) {
                const int c = p / (EXT * HALO), rr = p - c * (EXT * HALO);
                const int i = rr / HALO, j = rr - i * HALO;
                lat[c * LPS + i * LRS + j] = lat[c * LPS + i * LRS + (16 - j)];
            }
        } else if (xe1) {
            for (int p = tid; p < 3 * EXT * HALO; p += BLK) {
                const int c = p / (EXT * HALO), rr = p - c * (EXT * HALO);
                const int i = rr / HALO, j2 = rr - i * HALO;
                lat[c * LPS + i * LRS + 40 + j2] = lat[c * LPS + i * LRS + (38 - j2)];
            }
        }
        __syncthreads();
        if (ye0) {
            for (int p = tid; p < 3 * HALO * EXT; p += BLK) {
                const int c = p / (HALO * EXT), rr = p - c * (HALO * EXT);
                const int i = rr / EXT, j = rr - i * EXT;
                lat[c * LPS + i * LRS + j] = lat[c * LPS + (16 - i) * LRS + j];
            }
        } else if (ye1) {
            for (int p = tid; p < 3 * HALO * EXT; p += BLK) {
                const int c = p / (HALO * EXT), rr = p - c * (HALO * EXT);
                const int i2 = rr / EXT, j = rr - i2 * EXT;
                lat[c * LPS + (40 + i2) * LRS + j] = lat[c * LPS + (38 - i2) * LRS + j];
            }
        }
        __syncthreads();
    }

    // ---- fused sub-iterations (2 barriers each, all offsets precomputed) ----
    #pragma unroll
    for (int s = 0; s < K; ++s) {
        if (s >= m) break;

        // stage 1: rb = inp * rcp(conv(lat, k)), fixed pairs, guard 2s<=mrg
        #pragma unroll
        for (int up = 0; up < 5; ++up) {
            if (2 * s <= s1mrg[up]) {
                const int lo = s1lat[up];
                const int ro = s1rb[up];
                #pragma unroll
                for (int c = 0; c < 3; ++c) {
                    const float* lc = &lat[c * LPS + lo];
                    float a0 = 0.f, a1 = 0.f;
                    #pragma unroll
                    for (int dy = 0; dy < 3; ++dy) {
                        const float2 A  = *(const float2*)(lc + (dy - 1) * LRS - 1);
                        const float2 Bv = *(const float2*)(lc + (dy - 1) * LRS + 1);
                        const float w0 = gk[(dy * 3 + 0) * 3 + c];
                        const float w1 = gk[(dy * 3 + 1) * 3 + c];
                        const float w2 = gk[(dy * 3 + 2) * 3 + c];
                        a0 = fmaf(A.x, w0, fmaf(A.y, w1, fmaf(Bv.x, w2, a0)));
                        a1 = fmaf(A.y, w0, fmaf(Bv.x, w1, fmaf(Bv.y, w2, a1)));
                    }
                    const float r0 = ir[up][c]     * __builtin_amdgcn_rcpf(a0);
                    const float r1 = ir[up][3 + c] * __builtin_amdgcn_rcpf(a1);
                    *(__half2*)&rbt[c * RPS + ro] = __floats2half2_rn(r0, r1);
                }
            }
        }
        __syncthreads();

        // stage 2: e = conv(rb, kf); lat *= e; esum over interior.
        // rbt local col of ext x is x-1: output ext col j needs local
        // j-2..j+1 => q0 = (j-2,j-1), q1 = (j,j+1).
        float esum = 0.f;
        #pragma unroll
        for (int up = 0; up < 4; ++up) {
            if (2 * s <= s2mrg[up]) {
                const int ro = s2rb[up];
                const int lo = s2lat[up];
                const int mk = s2msk[up];
                #pragma unroll
                for (int c = 0; c < 3; ++c) {
                    float e0 = 0.f, e1 = 0.f;
                    #pragma unroll
                    for (int dy = 0; dy < 3; ++dy) {
                        const __half2* Rr = (const __half2*)
                            &rbt[c * RPS + ro + dy * RRS];
                        const float2 q0 = __half22float2(Rr[0]);
                        const float2 q1 = __half22float2(Rr[1]);
                        const float w0 = gkf[(dy * 3 + 0) * 3 + c];
                        const float w1 = gkf[(dy * 3 + 1) * 3 + c];
                        const float w2 = gkf[(dy * 3 + 2) * 3 + c];
                        e0 = fmaf(q0.x, w0, fmaf(q0.y, w1, fmaf(q1.x, w2, e0)));
                        e1 = fmaf(q0.y, w0, fmaf(q1.x, w1, fmaf(q1.y, w2, e1)));
                    }
                    float2* Lp = (float2*)&lat[c * LPS + lo];
                    float2 lv = *Lp;
                    lv.x *= e0; lv.y *= e1;
                    *Lp = lv;
                    esum += (mk & 1) ? e0 : 0.f;
                    esum += (mk & 2) ? e1 : 0.f;
                }
            }
        }
        if (wr_part) {
            #pragma unroll
            for (int off = 32; off; off >>= 1) esum += __shfl_down(esum, off, 64);
            if (lane == 0) wred[wid] = esum;
        }
        __syncthreads();     // lat writes done AND wred ready
        if (wr_part && tid == 0)
            part[(base + s) * NBLKS + b] = wred[0] + wred[1] + wred[2] + wred[3];
    }

    // ---- write interior [8,40)^2 to dst ----
    for (int p = tid; p < 1024; p += BLK) {
        const int i = p >> 5, j = p & 31;
        const int l = (i + HALO) * LRS + (j + HALO);
        float* op = dst + nbase + ((size_t)(ty0 + i) * W + (tx0 + j)) * 3;
        op[0] = lat[l];
        op[1] = lat[LPS + l];
        op[2] = lat[2 * LPS + l];
    }
}

extern "C" void kernel_launch(void* const* d_in, const int* in_sizes, int n_in,
                              void* d_out, int out_size, void* d_ws, size_t ws_size,
                              hipStream_t stream) {
    const float* inputs = (const float*)d_in[0];
    const float* gk     = (const float*)d_in[1];
    const float* gkf    = (const float*)d_in[2];
    float* out = (float*)d_out;

    // ws: [0 .. 128KB) iteration partials [30][1024] | buffer A | buffer B
    char* ws = (char*)d_ws;
    float* part = (float*)ws;
    float* A    = (float*)(ws + 131072);
    float* Bb   = (float*)(ws + 131072 + (size_t)TOTAL * sizeof(float));

    // period-3 schedule; X[g] = latent at start of group g. X[8] = out.
    const float* X[9] = { inputs, A, out, Bb, A, out, Bb, A, out };

    for (int g = 0; g < 9; ++g) {
        const float* s  = X[(g == 8) ? 7 : g];
        const float* sp = X[(g == 0) ? 0 : g - 1];
        float*       d  = (float*)((g == 8) ? X[8] : X[g + 1]);
        rl_group<<<NBLKS, BLK, 0, stream>>>(inputs, gk, gkf, s, sp, d, part, g);
    }
}

// Round 11
// 419.411 us; speedup vs baseline: 15.3830x; 1.2144x over previous
//
#include <hip/hip_runtime.h>
#include <hip/hip_fp16.h>

#define NB     4
#define H      512
#define W      512
#define ITERS  30
#define K      4             // max iterations fused per dispatch
#define TOLF   1e-05f
#define TOTAL  (NB*H*W*3)    // 3,145,728
#define BLK    512
#define NWAVES (BLK/64)      // 8
#define NBLKS  1024          // 4 images x 16x16 tiles of 32x32
#define HALO   8
#define EXT    48            // 32 + 2*HALO
#define LRS    48
#define LPS    (48*48)       // 2304
#define RRS    46            // rbt row stride (ext-1 coords, halfs)
#define RPS    (46*46)       // 2116
#define NP1    1058          // stage-1 pairs: 46 rows x 23 pair-cols
#define NP2    968           // stage-2 pairs: 44 rows x 22 pair-cols
#define S1S    3             // ceil(NP1/BLK)
#define S2S    2             // ceil(NP2/BLK)
#define TBIG   1000000

__device__ __forceinline__ int refl(int v, int n) {
    if (v < 0)  return -v;
    if (v >= n) return 2 * n - 2 - v;
    return v;
}

// One dispatch = up to K=4 fused RL iterations on a 32x32 tile, halo-8.
// R11: BLK=512 @ launch_bounds(512,8) -> 4 blocks/CU x 8 waves = 32 waves/CU
// (100% occupancy cap; LDS 40.4 KB is the 4-block limiter). Offsets
// precomputed (s-invariant; rbt in ext-1 coords); inputs re-loaded in-loop
// (L2-resident; latency hidden by the added waves). Symmetric Gaussian =>
// reflection commutes with conv (mirror band staged once). done-flag:
// optimistic run + deterministic partials scan; firing in the previous
// group => recompute from that group's intact source (period-3 schedule).
__global__ __launch_bounds__(BLK, 8) void rl_group(
    const float* __restrict__ inputs,
    const float* __restrict__ gk,
    const float* __restrict__ gkf,
    const float* __restrict__ src,       // latent at group start
    const float* __restrict__ src_prev,  // latent at PREVIOUS group start
    float* __restrict__ dst,
    float* __restrict__ part,            // [30][1024] iteration partials
    int g)                               // 0..7 compute, 8 fixup
{
    __shared__ float  lat[3 * LPS];      // 27648 B
    __shared__ __half rbt[3 * RPS];      // 12696 B
    __shared__ float  wred[NWAVES];
    __shared__ int    s_tstar;

    const int tid  = threadIdx.x;
    const int lane = tid & 63;
    const int wid  = tid >> 6;
    const int b    = blockIdx.x;
    const int n    = b >> 8;
    const int rtile= b & 255;
    const int ty0  = (rtile >> 4) << 5;
    const int tx0  = (rtile & 15) << 5;
    const bool xe0 = (tx0 == 0), xe1 = (tx0 + 32 == W);
    const bool ye0 = (ty0 == 0), ye1 = (ty0 + 32 == H);
    const bool edge = xe0 | xe1 | ye0 | ye1;
    const size_t nbase = (size_t)n * (H * W * 3);
    const float* inp_n = inputs + nbase;

    const int base      = (4 * g < ITERS) ? 4 * g : ITERS;
    const int prev_base = (g > 0) ? 4 * (g - 1) : 0;

    // ---- deterministic scan: first firing iteration among prior groups ----
    int tstar = TBIG;
    if (g > 0) {
        const int tmax = base;
        if (tid == 0) s_tstar = TBIG;
        __syncthreads();
        for (int t = wid; t < tmax; t += NWAVES) {
            double a = 0.0;
            for (int q = lane; q < NBLKS; q += 64)
                a += (double)part[t * NBLKS + q];
            #pragma unroll
            for (int off = 32; off; off >>= 1) a += __shfl_down(a, off, 64);
            if (lane == 0) {
                const float mean = (float)(a / (double)TOTAL);
                if (fabsf(1.0f - mean) < TOLF) atomicMin(&s_tstar, t);
            }
        }
        __syncthreads();
        tstar = s_tstar;
    }

    // ---- mode decision (block-uniform, identical across all blocks) ----
    int m;
    const float* lsrc;
    bool wr_part;
    if (g == 0) {
        m = K; lsrc = src; wr_part = true;
    } else if (tstar >= base) {
        if (g == 8) return;
        m = (ITERS - base < K) ? (ITERS - base) : K;
        lsrc = src; wr_part = true;
    } else if (tstar >= prev_base) {
        m = tstar - prev_base + 1; lsrc = src_prev; wr_part = false;
    } else {
        if (g == 8) return;
        for (int p = tid; p < 1024; p += BLK) {
            const int i = p >> 5, j = p & 31;
            const size_t o = nbase + ((size_t)(ty0 + i) * W + (tx0 + j)) * 3;
            dst[o] = src[o]; dst[o + 1] = src[o + 1]; dst[o + 2] = src[o + 2];
        }
        return;
    }

    // ---- fixed stage-1 pair metadata (offsets only; inputs loaded in-loop)
    // pair q: i = q/23 + 1 in [1,47), j = 2*(q%23) + 1 (odd)
    int s1lat[S1S], s1rb[S1S], s1mrg[S1S], s1o0[S1S], s1o1[S1S];
    #pragma unroll
    for (int up = 0; up < S1S; ++up) {
        const int q = tid + up * BLK;
        s1mrg[up] = -1;
        if (q < NP1) {
            const int i = q / 23 + 1;
            const int j = 2 * (q - (i - 1) * 23) + 1;
            s1lat[up] = i * LRS + j;
            s1rb[up]  = (i - 1) * RRS + (j - 1);
            int mg = i - 1;
            mg = min(mg, 46 - i); mg = min(mg, j - 1); mg = min(mg, 45 - j);
            s1mrg[up] = mg;
            const int ry  = refl(ty0 - HALO + i, H);
            const int rx0 = refl(tx0 - HALO + j, W);
            const int rx1 = refl(tx0 - HALO + j + 1, W);
            s1o0[up] = (ry * W + rx0) * 3;
            s1o1[up] = (ry * W + rx1) * 3;
        }
    }

    // ---- fixed stage-2 pair metadata ----
    // pair q: i = q/22 + 2 in [2,46), j = 2*(q%22) + 2 (even)
    int s2lat[S2S], s2rb[S2S], s2mrg[S2S], s2msk[S2S];
    #pragma unroll
    for (int up = 0; up < S2S; ++up) {
        const int q = tid + up * BLK;
        s2mrg[up] = -1; s2msk[up] = 0;
        if (q < NP2) {
            const int i = q / 22 + 2;
            const int j = 2 * (q - (i - 2) * 22) + 2;
            s2lat[up] = i * LRS + j;
            s2rb[up]  = (i - 2) * RRS + (j - 2);
            int mg = i - 2;
            mg = min(mg, 45 - i); mg = min(mg, j - 2); mg = min(mg, 44 - j);
            s2mrg[up] = mg;
            const bool iok = ((unsigned)(i - HALO) < 32u);
            s2msk[up] = (iok && ((unsigned)(j - HALO) < 32u) ? 1 : 0)
                      | (iok && ((unsigned)(j + 1 - HALO) < 32u) ? 2 : 0);
        }
    }

    // ---- stage 48x48 latent tile (in-image part) ----
    const float* s_n = lsrc + nbase;
    for (int p = tid; p < EXT * EXT; p += BLK) {
        const int i = p / EXT, j = p - i * EXT;
        const int gy = ty0 - HALO + i, gx = tx0 - HALO + j;
        if ((unsigned)gy < (unsigned)H && (unsigned)gx < (unsigned)W) {
            const float* sp = s_n + ((size_t)gy * W + gx) * 3;
            const int l = i * LRS + j;
            lat[l]           = sp[0];
            lat[LPS + l]     = sp[1];
            lat[2 * LPS + l] = sp[2];
        }
    }
    __syncthreads();

    // ---- mirror fixups (once): columns, then rows ----
    if (edge) {
        if (xe0) {
            for (int p = tid; p < 3 * EXT * HALO; p += BLK) {
                const int c = p / (EXT * HALO), rr = p - c * (EXT * HALO);
                const int i = rr / HALO, j = rr - i * HALO;
                lat[c * LPS + i * LRS + j] = lat[c * LPS + i * LRS + (16 - j)];
            }
        } else if (xe1) {
            for (int p = tid; p < 3 * EXT * HALO; p += BLK) {
                const int c = p / (EXT * HALO), rr = p - c * (EXT * HALO);
                const int i = rr / HALO, j2 = rr - i * HALO;
                lat[c * LPS + i * LRS + 40 + j2] = lat[c * LPS + i * LRS + (38 - j2)];
            }
        }
        __syncthreads();
        if (ye0) {
            for (int p = tid; p < 3 * HALO * EXT; p += BLK) {
                const int c = p / (HALO * EXT), rr = p - c * (HALO * EXT);
                const int i = rr / EXT, j = rr - i * EXT;
                lat[c * LPS + i * LRS + j] = lat[c * LPS + (16 - i) * LRS + j];
            }
        } else if (ye1) {
            for (int p = tid; p < 3 * HALO * EXT; p += BLK) {
                const int c = p / (HALO * EXT), rr = p - c * (HALO * EXT);
                const int i2 = rr / EXT, j = rr - i2 * EXT;
                lat[c * LPS + (40 + i2) * LRS + j] = lat[c * LPS + (38 - i2) * LRS + j];
            }
        }
        __syncthreads();
    }

    // ---- fused sub-iterations (2 barriers each, offsets precomputed) ----
    #pragma unroll
    for (int s = 0; s < K; ++s) {
        if (s >= m) break;

        // stage 1: rb = inp * rcp(conv(lat, k)), fixed pairs, guard 2s<=mrg
        #pragma unroll
        for (int up = 0; up < S1S; ++up) {
            if (2 * s <= s1mrg[up]) {
                const int lo = s1lat[up];
                const int ro = s1rb[up];
                const float* pa = inp_n + s1o0[up];
                const float* pb = inp_n + s1o1[up];
                float ia0 = pa[0], ia1 = pa[1], ia2 = pa[2];
                float ib0 = pb[0], ib1 = pb[1], ib2 = pb[2];
                #pragma unroll
                for (int c = 0; c < 3; ++c) {
                    const float* lc = &lat[c * LPS + lo];
                    float a0 = 0.f, a1 = 0.f;
                    #pragma unroll
                    for (int dy = 0; dy < 3; ++dy) {
                        const float2 A  = *(const float2*)(lc + (dy - 1) * LRS - 1);
                        const float2 Bv = *(const float2*)(lc + (dy - 1) * LRS + 1);
                        const float w0 = gk[(dy * 3 + 0) * 3 + c];
                        const float w1 = gk[(dy * 3 + 1) * 3 + c];
                        const float w2 = gk[(dy * 3 + 2) * 3 + c];
                        a0 = fmaf(A.x, w0, fmaf(A.y, w1, fmaf(Bv.x, w2, a0)));
                        a1 = fmaf(A.y, w0, fmaf(Bv.x, w1, fmaf(Bv.y, w2, a1)));
                    }
                    const float i0 = (c == 0) ? ia0 : (c == 1) ? ia1 : ia2;
                    const float i1 = (c == 0) ? ib0 : (c == 1) ? ib1 : ib2;
                    const float r0 = i0 * __builtin_amdgcn_rcpf(a0);
                    const float r1 = i1 * __builtin_amdgcn_rcpf(a1);
                    *(__half2*)&rbt[c * RPS + ro] = __floats2half2_rn(r0, r1);
                }
            }
        }
        __syncthreads();

        // stage 2: e = conv(rb, kf); lat *= e; esum over interior.
        // rbt local col of ext x is x-1: output ext col j needs local
        // j-2..j+1 => q0 = (j-2,j-1), q1 = (j,j+1).
        float esum = 0.f;
        #pragma unroll
        for (int up = 0; up < S2S; ++up) {
            if (2 * s <= s2mrg[up]) {
                const int ro = s2rb[up];
                const int lo = s2lat[up];
                const int mk = s2msk[up];
                #pragma unroll
                for (int c = 0; c < 3; ++c) {
                    float e0 = 0.f, e1 = 0.f;
                    #pragma unroll
                    for (int dy = 0; dy < 3; ++dy) {
                        const __half2* Rr = (const __half2*)
                            &rbt[c * RPS + ro + dy * RRS];
                        const float2 q0 = __half22float2(Rr[0]);
                        const float2 q1 = __half22float2(Rr[1]);
                        const float w0 = gkf[(dy * 3 + 0) * 3 + c];
                        const float w1 = gkf[(dy * 3 + 1) * 3 + c];
                        const float w2 = gkf[(dy * 3 + 2) * 3 + c];
                        e0 = fmaf(q0.x, w0, fmaf(q0.y, w1, fmaf(q1.x, w2, e0)));
                        e1 = fmaf(q0.y, w0, fmaf(q1.x, w1, fmaf(q1.y, w2, e1)));
                    }
                    float2* Lp = (float2*)&lat[c * LPS + lo];
                    float2 lv = *Lp;
                    lv.x *= e0; lv.y *= e1;
                    *Lp = lv;
                    esum += (mk & 1) ? e0 : 0.f;
                    esum += (mk & 2) ? e1 : 0.f;
                }
            }
        }
        if (wr_part) {
            #pragma unroll
            for (int off = 32; off; off >>= 1) esum += __shfl_down(esum, off, 64);
            if (lane == 0) wred[wid] = esum;
        }
        __syncthreads();     // lat writes done AND wred ready
        if (wr_part && tid == 0) {
            float t = 0.f;
            #pragma unroll
            for (int w2 = 0; w2 < NWAVES; ++w2) t += wred[w2];
            part[(base + s) * NBLKS + b] = t;
        }
    }

    // ---- write interior [8,40)^2 to dst ----
    for (int p = tid; p < 1024; p += BLK) {
        const int i = p >> 5, j = p & 31;
        const int l = (i + HALO) * LRS + (j + HALO);
        float* op = dst + nbase + ((size_t)(ty0 + i) * W + (tx0 + j)) * 3;
        op[0] = lat[l];
        op[1] = lat[LPS + l];
        op[2] = lat[2 * LPS + l];
    }
}

extern "C" void kernel_launch(void* const* d_in, const int* in_sizes, int n_in,
                              void* d_out, int out_size, void* d_ws, size_t ws_size,
                              hipStream_t stream) {
    const float* inputs = (const float*)d_in[0];
    const float* gk     = (const float*)d_in[1];
    const float* gkf    = (const float*)d_in[2];
    float* out = (float*)d_out;

    // ws: [0 .. 128KB) iteration partials [30][1024] | buffer A | buffer B
    char* ws = (char*)d_ws;
    float* part = (float*)ws;
    float* A    = (float*)(ws + 131072);
    float* Bb   = (float*)(ws + 131072 + (size_t)TOTAL * sizeof(float));

    // period-3 schedule; X[g] = latent at start of group g. X[8] = out.
    const float* X[9] = { inputs, A, out, Bb, A, out, Bb, A, out };

    for (int g = 0; g < 9; ++g) {
        const float* s  = X[(g == 8) ? 7 : g];
        const float* sp = X[(g == 0) ? 0 : g - 1];
        float*       d  = (float*)((g == 8) ? X[8] : X[g + 1]);
        rl_group<<<NBLKS, BLK, 0, stream>>>(inputs, gk, gkf, s, sp, d, part, g);
    }
}